// Round 1
// baseline (201.477 us; speedup 1.0000x reference)
//
#include <hip/hip_runtime.h>
#include <hip/hip_bf16.h>
#include <stdint.h>

#define TKS    4096   // tokens = 2*2048
#define KD     4096   // in_features
#define NSF    410    // split_f
#define NPARTS 10
#define OUTF   4096

#define BM 32
#define BN 64
#define BK 64

typedef unsigned short u16;
typedef __attribute__((ext_vector_type(8))) short bf16x8;
typedef __attribute__((ext_vector_type(4))) float f32x4;

// ---- workspace layout (~37.8 MB) ----
#define WS_XB  0                                     // u16[4096*4096]  granule bf16 x (32-row tiles)
#define WS_BSW ((size_t)TKS * KD * 2)                // u16[512*4096]   granule bf16 Wfc (64-row tiles)
#define WS_WSL (WS_BSW + (size_t)512 * KD * 2)       // u16[16*4096]    granule bf16 Wsel
#define WS_WEX (WS_WSL + (size_t)16 * KD * 2)        // u16[16*4096]    granule bf16 Wexp^T (+bexp row 10)

__device__ inline u16 f2bf(float f) {
    union { __hip_bfloat16 b; u16 u; } cv;
    cv.b = __float2bfloat16(f);
    return cv.u;
}

typedef __attribute__((address_space(3))) unsigned int as3_uint;
typedef __attribute__((address_space(1))) unsigned int as1_uint;
__device__ inline void gl_lds16(const void* g, void* l) {
    __builtin_amdgcn_global_load_lds((as1_uint*)(uintptr_t)g,
                                     (as3_uint*)(uintptr_t)l, 16, 0, 0);
}

// 64-row tile granule g in [0,512): slot=g>>6 = hi*4+ks*2+lo
// row = hi*32+lo*16+(g&15) ; col = ks*32+((g>>4)&3)*8   (conflict-free, proven R2-R5)
__device__ inline int g_row(int g) { int s = g >> 6; return (s >> 2) * 32 + (s & 1) * 16 + (g & 15); }
__device__ inline int g_col(int g) { int s = g >> 6; return ((s >> 1) & 1) * 32 + ((g >> 4) & 3) * 8; }

// ============ prep_w: Wsel/Wexp -> 16-row granule-tiled bf16 =================
__global__ __launch_bounds__(256) void prep_w(const float* __restrict__ Wsel,
                                              const float* __restrict__ Wexp,
                                              const float* __restrict__ bexp,
                                              u16* __restrict__ wselb,
                                              u16* __restrict__ wexpb) {
    const int kt = blockIdx.x;           // 0..63
    const int tid = threadIdx.x;
    const int g  = tid & 127;
    const int ml = g & 15;
    const int col = kt * 64 + (g >> 6) * 32 + ((g >> 4) & 3) * 8;
    u16 h[8];
    if (tid < 128) {
#pragma unroll
        for (int j = 0; j < 8; ++j)
            h[j] = (ml < NPARTS) ? f2bf(Wsel[(size_t)ml * KD + col + j]) : (u16)0;
        *(uint4*)&wselb[((size_t)kt * 128 + g) * 8] = *(uint4*)h;
    } else {
#pragma unroll
        for (int j = 0; j < 8; ++j)
            h[j] = (ml < NPARTS) ? f2bf(Wexp[(size_t)(col + j) * NPARTS + ml])
                 : (ml == NPARTS ? f2bf(bexp[col + j]) : (u16)0);
        *(uint4*)&wexpb[((size_t)kt * 128 + g) * 8] = *(uint4*)h;
    }
}

// ============ retile_b: Wfc (f32) -> bsw (bf16 granule-tiled, rows>=410 zero)
__global__ __launch_bounds__(256) void retile_b(const float* __restrict__ Wfc,
                                                u16* __restrict__ bsw) {
    const int kt = blockIdx.x & 63, rb = blockIdx.x >> 6;
    const int tid = threadIdx.x;
    u16* tout = bsw + ((size_t)(rb * 64 + kt) * 512) * 8;
#pragma unroll
    for (int j = 0; j < 2; ++j) {
        const int g = j * 256 + tid;
        const int r = rb * 64 + g_row(g);
        uint4 pk = make_uint4(0u, 0u, 0u, 0u);
        if (r < NSF) {
            const float* src = Wfc + (size_t)r * KD + kt * 64 + g_col(g);
            float4 v0 = *(const float4*)src;
            float4 v1 = *(const float4*)(src + 4);
            u16 h[8] = { f2bf(v0.x), f2bf(v0.y), f2bf(v0.z), f2bf(v0.w),
                         f2bf(v1.x), f2bf(v1.y), f2bf(v1.z), f2bf(v1.w) };
            pk = *(uint4*)h;
        }
        *(uint4*)&tout[(size_t)g * 8] = pk;
    }
}

// ============ retile_x: x (f32) -> xb (bf16, 32-row granule tiles) ===========
__global__ __launch_bounds__(256) void retile_x(const float* __restrict__ x,
                                                u16* __restrict__ xb) {
    const int kt = blockIdx.x & 63, tb = blockIdx.x >> 6;   // tb 0..127
    const int g = threadIdx.x;                              // granule 0..255
    const int slot = g >> 6;                                // ks*2+lo
    const int row = (slot & 1) * 16 + (g & 15);
    const int col = (slot >> 1) * 32 + ((g >> 4) & 3) * 8;
    const float* src = x + (size_t)(tb * 32 + row) * KD + kt * 64 + col;
    float4 v0 = *(const float4*)src;
    float4 v1 = *(const float4*)(src + 4);
    u16 h[8] = { f2bf(v0.x), f2bf(v0.y), f2bf(v0.z), f2bf(v0.w),
                 f2bf(v1.x), f2bf(v1.y), f2bf(v1.z), f2bf(v1.w) };
    *(uint4*)&xb[((size_t)(tb * 64 + kt) * 256 + g) * 8] = *(uint4*)h;
}

// ============ main: A = x·Wfc^T + in-loop sx/G/c via MFMA side-accs ==========
// R-this-round: counted-vmcnt pipeline (raw s_barrier + s_waitcnt vmcnt(4);
// prefetch never drains to 0 inside the loop) + LDS 36.9->32.0 KB by aliasing
// the post-loop sxs/Gs/cs tables onto the staging buffers -> 5 blocks/CU.
// grid 896 = 7 fb x 128 tb (fb-major for B L2 reuse); 4 waves:
// mt = w&1 (16-row m-tile), wc = w>>1 (32-col half).
__global__ __launch_bounds__(256, 5) void main_kernel(const u16* __restrict__ xb,
                                                      const u16* __restrict__ bsw,
                                                      const u16* __restrict__ wselb,
                                                      const u16* __restrict__ wexpb,
                                                      const float* __restrict__ bsel,
                                                      const float* __restrict__ bfc,
                                                      float* __restrict__ out) {
    // 32 KB staging; post-loop f32 tables alias the head (safe: loop is fully
    // barriered, tables only touched after the final end-of-iter barrier).
    __shared__ __align__(16) u16 smem[16384];
    u16* const Asb = smem;              // [2][2048]  2 x 4 KB
    u16* const Bsb = smem + 4096;       // [2][4096]  2 x 8 KB
    u16* const Wlb = smem + 12288;      // [2][1024]  2 x 2 KB (Wsel slab)
    u16* const Web = smem + 14336;      // [2][1024]  2 x 2 KB (Wexp^T slab)
    float* const sxs = (float*)smem;            // [32][NPARTS]  1280 B
    float* const Gs  = (float*)(smem + 640);    // [64][NPARTS]  2560 B
    float* const cs  = (float*)(smem + 1920);   // [64]           256 B

    const int tid = threadIdx.x;
    const int fb  = blockIdx.x >> 7;    // 0..6
    const int tb  = blockIdx.x & 127;   // 0..127

    const int lane = tid & 63;
    const int w  = tid >> 6;
    const int mt = w & 1, wc = w >> 1;
    const int q  = lane >> 4, ml = lane & 15;

    f32x4 acc[2]   = { (f32x4){0.f,0.f,0.f,0.f}, (f32x4){0.f,0.f,0.f,0.f} };
    f32x4 accsx    = (f32x4){0.f,0.f,0.f,0.f};
    f32x4 accG[2]  = { (f32x4){0.f,0.f,0.f,0.f}, (f32x4){0.f,0.f,0.f,0.f} };

    const u16* ab = xb  + (size_t)tb * 131072;   // 64 slabs x 256 granules x 8
    const u16* bb = bsw + (size_t)fb * 262144;   // 64 slabs x 512 granules x 8

    // Stage slab it1 into buffer nb: exactly 4 uniform global_load_lds / thread
    // (1 A + 2 B + 1 W; the tid<128 branch is wave-uniform).
#define STAGE(it1, nb) do {                                                      \
        const size_t ao_ = (size_t)(it1) * 2048;                                 \
        const size_t bo_ = (size_t)(it1) * 4096;                                 \
        const size_t wo_ = (size_t)(it1) * 1024;                                 \
        gl_lds16(ab + ao_ + tid * 8,        &Asb[(nb) * 2048 + tid * 8]);        \
        gl_lds16(bb + bo_ + tid * 8,        &Bsb[(nb) * 4096 + tid * 8]);        \
        gl_lds16(bb + bo_ + (256 + tid) * 8,&Bsb[(nb) * 4096 + (256 + tid) * 8]);\
        if (tid < 128) gl_lds16(wselb + wo_ + tid * 8,                           \
                                &Wlb[(nb) * 1024 + tid * 8]);                    \
        else           gl_lds16(wexpb + wo_ + (tid - 128) * 8,                   \
                                &Web[(nb) * 1024 + (tid - 128) * 8]);            \
    } while (0)

    STAGE(0, 0);

#pragma unroll 2
    for (int it = 0; it < KD / BK; ++it) {
        const int buf = it & 1;
        // Issue next-slab prefetch into buf^1. Safe: the end-barrier of iter
        // it-1 (below) guaranteed all waves finished their ds_reads of buf^1.
        if (it + 1 < KD / BK) {
            STAGE(it + 1, buf ^ 1);
            // wait for THIS slab's 4 loads; next slab's 4 stay in flight
            asm volatile("s_waitcnt vmcnt(4)" ::: "memory");
        } else {
            asm volatile("s_waitcnt vmcnt(0)" ::: "memory");
        }
        __builtin_amdgcn_s_barrier();       // all waves: slab `it` visible in LDS
        asm volatile("" ::: "memory");
#pragma unroll
        for (int ks = 0; ks < 2; ++ks) {
            bf16x8 av  = *(const bf16x8*)&Asb[buf * 2048 + ((ks * 2 + mt) * 64 + lane) * 8];
            bf16x8 bv0 = *(const bf16x8*)&Bsb[buf * 4096 + ((wc * 4 + ks * 2 + 0) * 64 + lane) * 8];
            bf16x8 bv1 = *(const bf16x8*)&Bsb[buf * 4096 + ((wc * 4 + ks * 2 + 1) * 64 + lane) * 8];
            acc[0] = __builtin_amdgcn_mfma_f32_16x16x32_bf16(av, bv0, acc[0], 0, 0, 0);
            acc[1] = __builtin_amdgcn_mfma_f32_16x16x32_bf16(av, bv1, acc[1], 0, 0, 0);
            if (wc == 0) {   // sx for this wave's 16 token rows
                bf16x8 wf = *(const bf16x8*)&Wlb[buf * 1024 + (ks * 64 + lane) * 8];
                accsx = __builtin_amdgcn_mfma_f32_16x16x32_bf16(av, wf, accsx, 0, 0, 0);
            }
            if (mt == 0) {   // G/c for this wave's 32 f-rows
                bf16x8 ef = *(const bf16x8*)&Web[buf * 1024 + (ks * 64 + lane) * 8];
                accG[0] = __builtin_amdgcn_mfma_f32_16x16x32_bf16(bv0, ef, accG[0], 0, 0, 0);
                accG[1] = __builtin_amdgcn_mfma_f32_16x16x32_bf16(bv1, ef, accG[1], 0, 0, 0);
            }
        }
        // End-of-iter barrier: guarantee this buffer's ds_reads are PHYSICALLY
        // complete (lgkmcnt(0)) before any wave overwrites it next iteration.
        asm volatile("s_waitcnt lgkmcnt(0)" ::: "memory");
        __builtin_amdgcn_s_barrier();
        asm volatile("" ::: "memory");
    }
#undef STAGE

    // ---- post-loop: publish sx/G/c to LDS tables (alias staging head) ----
    if (wc == 0 && ml < NPARTS) {
        const float bs = bsel[ml];
#pragma unroll
        for (int r = 0; r < 4; ++r)
            sxs[(mt * 16 + q * 4 + r) * NPARTS + ml] = accsx[r] + bs;
    }
    if (mt == 0) {
#pragma unroll
        for (int ni = 0; ni < 2; ++ni) {
#pragma unroll
            for (int r = 0; r < 4; ++r) {
                const int f = wc * 32 + ni * 16 + q * 4 + r;
                if (ml < NPARTS) Gs[f * NPARTS + ml] = accG[ni][r];
                else if (ml == NPARTS) {
                    const int fg = fb * BN + f;
                    cs[f] = accG[ni][r] + (fg < NSF ? bfc[fg] : 0.f);
                }
            }
        }
    }
    __syncthreads();

    // ---- epilogue: out[t, n*410+f] = A + sx[t][n]*G[f][n] + c[f] ----
#pragma unroll
    for (int ni = 0; ni < 2; ++ni) {
        const int fl = wc * 32 + ni * 16 + ml;
        const int fg = fb * BN + fl;
        if (fg >= NSF) continue;
        const float cv = cs[fl];
        float gv[NPARTS];
#pragma unroll
        for (int n = 0; n < NPARTS; ++n) gv[n] = Gs[fl * NPARTS + n];
#pragma unroll
        for (int r = 0; r < 4; ++r) {
            const int tl = mt * 16 + q * 4 + r;
            const float av = acc[ni][r] + cv;
            float* orow = out + (size_t)(tb * BM + tl) * OUTF;
#pragma unroll
            for (int n = 0; n < NPARTS; ++n) {
                int j = n * NSF + fg;
                if (j < OUTF) orow[j] = av + sxs[tl * NPARTS + n] * gv[n];
            }
        }
    }
}

extern "C" void kernel_launch(void* const* d_in, const int* in_sizes, int n_in,
                              void* d_out, int out_size, void* d_ws, size_t ws_size,
                              hipStream_t stream) {
    const float* x    = (const float*)d_in[0];
    const float* Wsel = (const float*)d_in[1];
    const float* bsel = (const float*)d_in[2];
    const float* Wexp = (const float*)d_in[3];
    const float* bexp = (const float*)d_in[4];
    const float* Wfc  = (const float*)d_in[5];
    const float* bfc  = (const float*)d_in[6];
    float* out = (float*)d_out;

    char* ws = (char*)d_ws;
    u16* xb    = (u16*)(ws + WS_XB);
    u16* bsw   = (u16*)(ws + WS_BSW);
    u16* wselb = (u16*)(ws + WS_WSL);
    u16* wexpb = (u16*)(ws + WS_WEX);

    prep_w<<<dim3(64), dim3(256), 0, stream>>>(Wsel, Wexp, bexp, wselb, wexpb);
    retile_b<<<dim3(7 * 64), dim3(256), 0, stream>>>(Wfc, bsw);
    retile_x<<<dim3(128 * 64), dim3(256), 0, stream>>>(x, xb);
    main_kernel<<<dim3(7 * 128), dim3(256), 0, stream>>>(xb, bsw, wselb, wexpb,
                                                         bsel, bfc, out);
}